// Round 16
// baseline (2092.286 us; speedup 1.0000x reference)
//
#include <hip/hip_runtime.h>
#include <cstdint>
#include <cstddef>

// ConvGRU autoencoder, round 16: r12 (best, 1166us) retiled to 1024 threads.
// Same schedule / cb map / weight placement / math as r12; 16 waves instead
// of 8 -> 4 waves/SIMD (2x latency hiding). Per-wave FTW halves (e1/d0: 2,
// e0/d1: 1) so total fragment-LDS traffic is unchanged while per-thread
// live state SHRINKS (acc arrays halve). Weight-fetch instruction count
// doubles (4 waves share each cot slice -> L1 hits).

#define F_ 128
#define T_ 100
#define B_ 64
#define ROWSP 130
#define CBSTR (ROWSP * 8)    // f16 per cb
#define CBBYTE (ROWSP * 16)  // bytes per cb
#define AT_OFF 104448
#define LDS_TOTAL (AT_OFF + 28 * CBBYTE)  // 162688

typedef _Float16 f16;
typedef __attribute__((ext_vector_type(4))) float f32x4;
typedef __attribute__((ext_vector_type(8))) _Float16 f16x8;
typedef __attribute__((ext_vector_type(4))) _Float16 f16x4;

#define MFMA(a, b, c) __builtin_amdgcn_mfma_f32_16x16x32_f16(a, b, c, 0, 0, 0)

__device__ __forceinline__ float exp2_(float x) { return __builtin_amdgcn_exp2f(x); }
__device__ __forceinline__ float rcp_(float x) { return __builtin_amdgcn_rcpf(x); }

#define KSG (-1.442695041f)  // sigmoid: sig(v) = rcp(1+exp2(v*KSG))
#define KTH (-2.885390082f)  // tanh:    tanh(v) = 2*rcp(1+exp2(v*KTH)) - 1

// cb base per (layer, ks%NC3); fragment cb = base + kb (kb = lane>>4). (r9)
__host__ __device__ constexpr int cbA(int lid, int km) {
  return lid == 0 ? (km ? 4 : 0)
       : lid == 1 ? (1 + km * 4)
       : lid == 2 ? (km * 4)
                  : (8 + km * 4);
}
__host__ __device__ constexpr int cbB(int lid, int km) {
  return lid == 0 ? (km ? 17 : 13)
       : lid == 1 ? (km == 0 ? 1 : 14 + km * 4)
       : lid == 2 ? (km < 2 ? km * 4 : 12 + km * 4)
                  : (km < 2 ? 8 + km * 4 : 20);
}

// Gate convs (R,U) over [x ; h]. Weights from regs (WREG) or LDS.
template <int LID, int FTW, int NK, int NC3, bool WREG>
__device__ __forceinline__ void convA_f(
    const f16* __restrict__ rdB,
    const f16x8* __restrict__ aR, const f16x8* __restrict__ aU,
    const f16* __restrict__ gR, const f16* __restrict__ gU,
    f32x4* __restrict__ accR, f32x4* __restrict__ accU) {
#pragma unroll
  for (int j = 0; j < FTW; ++j) {
    accR[j] = (f32x4){0.f, 0.f, 0.f, 0.f};
    accU[j] = (f32x4){0.f, 0.f, 0.f, 0.f};
  }
#pragma unroll
  for (int ks = 0; ks < NK; ++ks) {
    const int k = ks / NC3, km = ks % NC3;
    const f16* fb = rdB + cbA(LID, km) * CBSTR + k * 8;
    f16x8 bf[FTW];
#pragma unroll
    for (int j = 0; j < FTW; ++j) bf[j] = *(const f16x8*)(fb + j * 128);
    f16x8 wr, wu;
    if constexpr (WREG) { wr = aR[ks]; wu = aU[ks]; }
    else {
      wr = *(const f16x8*)(gR + ks * 512);
      wu = *(const f16x8*)(gU + ks * 512);
    }
#pragma unroll
    for (int j = 0; j < FTW; ++j) accR[j] = MFMA(wr, bf[j], accR[j]);
#pragma unroll
    for (int j = 0; j < FTW; ++j) accU[j] = MFMA(wu, bf[j], accU[j]);
  }
}

// Candidate conv over [x ; r*h]. Weights from regs (CREG) or LDS.
template <int LID, int FTW, int NK, int NC3, bool CREG>
__device__ __forceinline__ void convB_f(
    const f16* __restrict__ rdB, const f16x8* __restrict__ cR,
    const f16* __restrict__ cW, f32x4* __restrict__ accC) {
#pragma unroll
  for (int j = 0; j < FTW; ++j) accC[j] = (f32x4){0.f, 0.f, 0.f, 0.f};
#pragma unroll
  for (int ks = 0; ks < NK; ++ks) {
    const int k = ks / NC3, km = ks % NC3;
    const f16* fb = rdB + cbB(LID, km) * CBSTR + k * 8;
    f16x8 bf[FTW];
#pragma unroll
    for (int j = 0; j < FTW; ++j) bf[j] = *(const f16x8*)(fb + j * 128);
    f16x8 wc;
    if constexpr (CREG) wc = cR[ks];
    else wc = *(const f16x8*)(cW + ks * 512);
#pragma unroll
    for (int j = 0; j < FTW; ++j) accC[j] = MFMA(wc, bf[j], accC[j]);
  }
}

// rh = sigm(R)*h into cb RHCB (relative to wrB's base cb).
template <int FTW, int RHCB>
__device__ __forceinline__ void postA_f(const f32x4* __restrict__ accR,
                                        const f32x4 bR,
                                        const f32x4* __restrict__ hreg,
                                        char* __restrict__ wrB) {
#pragma unroll
  for (int j = 0; j < FTW; ++j) {
    f16x4 rh;
#pragma unroll
    for (int q = 0; q < 4; ++q) {
      const float r = rcp_(1.0f + exp2_(fmaf(accR[j][q], KSG, bR[q])));
      rh[q] = (f16)(r * hreg[j][q]);
    }
    *(f16x4*)(wrB + RHCB * CBBYTE + j * 256) = rh;
  }
}

// u = sigm(U); h = h + u*(tanh(C)-h); write h cb (+ y1 emit).
template <int FTW, int HCB, bool EMITY1>
__device__ __forceinline__ void postB_f(const f32x4* __restrict__ accU,
                                        const f32x4* __restrict__ accC,
                                        const f32x4 bU, const f32x4 bC,
                                        f32x4* __restrict__ hreg,
                                        char* __restrict__ wrB,
                                        f16* __restrict__ y1dst) {
#pragma unroll
  for (int j = 0; j < FTW; ++j) {
    f16x4 hh;
#pragma unroll
    for (int q = 0; q < 4; ++q) {
      const float u = rcp_(1.0f + exp2_(fmaf(accU[j][q], KSG, bU[q])));
      const float r = rcp_(1.0f + exp2_(fmaf(accC[j][q], KTH, bC[q])));
      const float h = hreg[j][q];
      const float s = fmaf(2.0f, r, -(1.0f + h));  // tanh(C) - h
      const float hn = fmaf(u, s, h);
      hreg[j][q] = hn;
      hh[q] = (f16)hn;
    }
    *(f16x4*)(wrB + HCB * CBBYTE + j * 256) = hh;
    if constexpr (EMITY1) *(f16x4*)(y1dst + j * 128) = hh;
  }
}

__global__ __launch_bounds__(1024, 1) void ae_kernel(
    const f16* __restrict__ xf, float* __restrict__ out,
    const f16* __restrict__ wgE0, const f16* __restrict__ wcE0,
    const float* __restrict__ bgE0, const float* __restrict__ bcE0,
    const f16* __restrict__ wgE1, const f16* __restrict__ wcE1,
    const float* __restrict__ bgE1, const float* __restrict__ bcE1,
    const f16* __restrict__ wgD0, const f16* __restrict__ wcD0,
    const float* __restrict__ bgD0, const float* __restrict__ bcD0,
    const f16* __restrict__ wgD1, const f16* __restrict__ wcD1,
    const float* __restrict__ bgD1, const float* __restrict__ bcD1,
    const float* __restrict__ fw, const float* __restrict__ fb,
    f16* __restrict__ y1g) {
  extern __shared__ char smem[];
  f16* aT = (f16*)(smem + AT_OFF);
  const int tid = threadIdx.x, b = blockIdx.x;
  const int w = tid >> 6, l = tid & 63;  // 16 waves
  const int m16 = l & 15, kb = l >> 4;

  // zero aT (28 cb)
  for (int i = tid; i < 28 * CBBYTE / 16; i += 1024)
    ((f32x4*)(smem + AT_OFF))[i] = (f32x4){0.f, 0.f, 0.f, 0.f};
  // encoder LDS weights: wgE0@0 (24576 B), wcE0@24576 (12288 B)
  for (int i = tid; i < 1536; i += 1024)
    ((f16x8*)(smem + 0))[i] = ((const f16x8*)wgE0)[i];
  for (int i = tid; i < 768; i += 1024)
    ((f16x8*)(smem + 24576))[i] = ((const f16x8*)wcE0)[i];

  // e1 gate + cand weights (compiler streams from L2; r9-proven placement)
  const int cot2 = w & 1, cot4 = w & 3;
  const int ft1 = w >> 1;   // 8 f-groups of 16 (FTW=1 layers: e0, d1)
  const int ftg2 = w >> 2;  // 4 f-groups of 32 (FTW=2 layers: e1, d0)
  f16x8 aR1[9], aU1[9], cE1[9];
#pragma unroll
  for (int ks = 0; ks < 9; ++ks) {
    aR1[ks] = ((const f16x8*)wgE1)[(cot4 * 9 + ks) * 64 + l];
    aU1[ks] = ((const f16x8*)wgE1)[((cot4 + 4) * 9 + ks) * 64 + l];
    cE1[ks] = ((const f16x8*)wcE1)[(cot4 * 9 + ks) * 64 + l];
  }
  // enc biases (scale folded)
  const int co2 = cot2 * 16 + kb * 4;
  const int co4 = cot4 * 16 + kb * 4;
  f32x4 bRe0, bUe0, bCe0, bRe1, bUe1, bCe1;
#pragma unroll
  for (int q = 0; q < 4; ++q) {
    bRe0[q] = bgE0[co2 + q] * KSG;
    bUe0[q] = bgE0[32 + co2 + q] * KSG;
    bCe0[q] = bcE0[co2 + q] * KTH;
    bRe1[q] = bgE1[co4 + q] * KSG;
    bUe1[q] = bgE1[64 + co4 + q] * KSG;
    bCe1[q] = bcE1[co4 + q] * KTH;
  }
  // per-thread LDS bases
  const f16* rdB2 = aT + kb * CBSTR + (ft1 * 16 + m16) * 8;
  const f16* rdB4 = aT + kb * CBSTR + (ftg2 * 32 + m16) * 8;
  char* wrB2 = (char*)aT + (cot2 * 2 + (kb >> 1)) * CBBYTE +
               (ft1 * 16 + m16 + 1) * 16 + (kb & 1) * 8;
  char* wrB4 = (char*)aT + (cot4 * 2 + (kb >> 1)) * CBBYTE +
               (ftg2 * 32 + m16 + 1) * 16 + (kb & 1) * 8;
  f16* y1t = y1g + (size_t)b * T_ * 8192 +
             ((cot4 * 2 + (kb >> 1)) * 128 + ftg2 * 32 + m16) * 8 + (kb & 1) * 4;
  const f16* gE0R = (const f16*)(smem + 0) + (cot2 * 6) * 512 + l * 8;
  const f16* gE0U = (const f16*)(smem + 0) + ((2 + cot2) * 6) * 512 + l * 8;
  const f16* cE0l = (const f16*)(smem + 24576) + (cot2 * 6) * 512 + l * 8;

  f32x4 h0r[1], h1r[2];
  h0r[0] = (f32x4){0.f, 0.f, 0.f, 0.f};
#pragma unroll
  for (int j = 0; j < 2; ++j) h1r[j] = (f32x4){0.f, 0.f, 0.f, 0.f};
  __syncthreads();

  // ================= encoder (4 windows/t) =================
  const f16* xb = xf + (size_t)b * T_ * F_;
  if (tid < F_) {  // ingest x(0)
    const f16 v = xb[tid];
    aT[(tid + 1) * 8] = v;
    aT[13 * CBSTR + (tid + 1) * 8] = v;
  }
  __syncthreads();
  for (int t = 0; t < T_; ++t) {
    // W2: e0 convA + postA ; issue x(t+1) -> reg
    f32x4 aR0g[1], aU0g[1];
    convA_f<0, 1, 6, 2, false>(rdB2, nullptr, nullptr, gE0R, gE0U, aR0g, aU0g);
    f16 xpre = (f16)0.f;
    if (t + 1 < T_ && tid < F_) xpre = xb[(t + 1) * F_ + tid];
    postA_f<1, 14>(aR0g, bRe0, h0r, wrB2);
    __syncthreads();
    // W3: e0 convB + postB
    f32x4 aC0[1];
    convB_f<0, 1, 6, 2, false>(rdB2, nullptr, cE0l, aC0);
    postB_f<1, 1, false>(aU0g, aC0, bUe0, bCe0, h0r, wrB2, nullptr);
    __syncthreads();
    // W4: e1 convA + postA ; write x(t+1) (cb0/13 not read here)
    f32x4 aR1g[2], aU1g[2];
    convA_f<1, 2, 9, 3, true>(rdB4, aR1, aU1, nullptr, nullptr, aR1g, aU1g);
    if (t + 1 < T_ && tid < F_) {
      aT[(tid + 1) * 8] = xpre;
      aT[13 * CBSTR + (tid + 1) * 8] = xpre;
    }
    postA_f<2, 18>(aR1g, bRe1, h1r, wrB4);
    __syncthreads();
    // W5: e1 convB + postB (+ y1 emit)
    f32x4 aC1[2];
    convB_f<1, 2, 9, 3, true>(rdB4, cE1, nullptr, aC1);
    postB_f<2, 5, true>(aU1g, aC1, bUe1, bCe1, h1r, wrB4,
                        y1t + (size_t)t * 8192);
    __syncthreads();
  }

  // ================= transition to decoder =================
  {  // hd0 init cols 64+ (= cb8-15, from h1r); hd1 init cols 128+ (cb16-19)
#pragma unroll
    for (int j = 0; j < 2; ++j) {
      f16x4 hh;
#pragma unroll
      for (int q = 0; q < 4; ++q) hh[q] = (f16)h1r[j][q];
      *(f16x4*)(wrB4 + 8 * CBBYTE + j * 256) = hh;
    }
    {
      f16x4 hh;
#pragma unroll
      for (int q = 0; q < 4; ++q) hh[q] = (f16)h0r[0][q];
      *(f16x4*)(wrB2 + 16 * CBBYTE) = hh;
    }
  }
  // dec LDS weights: wcD0@0 (49152 B), wgD1@49152 (36864 B), wcD1@86016
  for (int i = tid; i < 3072; i += 1024)
    ((f16x8*)(smem + 0))[i] = ((const f16x8*)wcD0)[i];
  for (int i = tid; i < 2304; i += 1024)
    ((f16x8*)(smem + 49152))[i] = ((const f16x8*)wgD1)[i];
  for (int i = tid; i < 1152; i += 1024)
    ((f16x8*)(smem + 86016))[i] = ((const f16x8*)wcD1)[i];
  // d0 gate weights (streamed; r9 placement)
  f16x8 aR0[12], aU0[12];
#pragma unroll
  for (int ks = 0; ks < 12; ++ks) {
    aR0[ks] = ((const f16x8*)wgD0)[(cot4 * 12 + ks) * 64 + l];
    aU0[ks] = ((const f16x8*)wgD0)[((cot4 + 4) * 12 + ks) * 64 + l];
  }
  // dec biases
  f32x4 bRd0, bUd0, bCd0, bRd1, bUd1, bCd1;
#pragma unroll
  for (int q = 0; q < 4; ++q) {
    bRd0[q] = bgD0[co4 + q] * KSG;
    bUd0[q] = bgD0[64 + co4 + q] * KSG;
    bCd0[q] = bcD0[co4 + q] * KTH;
    bRd1[q] = bgD1[co2 + q] * KSG;
    bUd1[q] = bgD1[32 + co2 + q] * KSG;
    bCd1[q] = bcD1[co2 + q] * KTH;
  }
  const f16* cD0l = (const f16*)(smem + 0) + (cot4 * 12) * 512 + l * 8;
  const f16* gD1R = (const f16*)(smem + 49152) + (cot2 * 9) * 512 + l * 8;
  const f16* gD1U = (const f16*)(smem + 49152) + ((2 + cot2) * 9) * 512 + l * 8;
  const f16* cD1l = (const f16*)(smem + 86016) + (cot2 * 9) * 512 + l * 8;
  const float fb0 = fb[0];
  __syncthreads();
  {  // ingest y1(0): 1024 threads x f16x8 = 8192 f16 exactly
    const f16x8* src = (const f16x8*)(y1g + (size_t)b * T_ * 8192);
    *(f16x8*)&aT[(tid >> 7) * CBSTR + ((tid & 127) + 1) * 8] = src[tid];
  }
  __syncthreads();

  // ================= decoder (4 windows/t; out shifted 1 window) ===========
  for (int t = 0; t < T_; ++t) {
    // W2: d0 convA + postA ; out(t-1) (cb16-19 stable) ; issue y1(t+1)
    f32x4 aRd0[2], aUd0[2];
    convA_f<2, 2, 12, 4, true>(rdB4, aR0, aU0, nullptr, nullptr, aRd0, aUd0);
    if (t >= 1 && tid < F_) {
      float s = fb0;
#pragma unroll
      for (int cb = 0; cb < 4; ++cb) {
        const f16x8 h8 = *(const f16x8*)&aT[(16 + cb) * CBSTR + (tid + 1) * 8];
#pragma unroll
        for (int q = 0; q < 8; ++q) s = fmaf(fw[cb * 8 + q], (float)h8[q], s);
      }
      out[((size_t)b * T_ + (t - 1)) * F_ + tid] = s;
    }
    f16x8 yp0 = {};
    if (t + 1 < T_) {
      const f16x8* src = (const f16x8*)(y1g + ((size_t)b * T_ + t + 1) * 8192);
      yp0 = src[tid];
    }
    postA_f<2, 20>(aRd0, bRd0, h1r, wrB4);
    __syncthreads();
    // W3: d0 convB + postB
    f32x4 aCd0[2];
    convB_f<2, 2, 12, 4, false>(rdB4, nullptr, cD0l, aCd0);
    postB_f<2, 8, false>(aUd0, aCd0, bUd0, bCd0, h1r, wrB4, nullptr);
    __syncthreads();
    // W4: d1 convA + postA ; write y1(t+1) -> cb0-7 (not read here)
    f32x4 aRd1[1], aUd1[1];
    convA_f<3, 1, 9, 3, false>(rdB2, nullptr, nullptr, gD1R, gD1U, aRd1, aUd1);
    if (t + 1 < T_)
      *(f16x8*)&aT[(tid >> 7) * CBSTR + ((tid & 127) + 1) * 8] = yp0;
    postA_f<1, 20>(aRd1, bRd1, h0r, wrB2);
    __syncthreads();
    // W5: d1 convB + postB
    f32x4 aCd1[1];
    convB_f<3, 1, 9, 3, false>(rdB2, nullptr, cD1l, aCd1);
    postB_f<1, 16, false>(aUd1, aCd1, bUd1, bCd1, h0r, wrB2, nullptr);
    __syncthreads();
  }
  if (tid < F_) {  // epilogue: out(T-1)
    float s = fb0;
#pragma unroll
    for (int cb = 0; cb < 4; ++cb) {
      const f16x8 h8 = *(const f16x8*)&aT[(16 + cb) * CBSTR + (tid + 1) * 8];
#pragma unroll
      for (int q = 0; q < 8; ++q) s = fmaf(fw[cb * 8 + q], (float)h8[q], s);
    }
    out[((size_t)b * T_ + (T_ - 1)) * F_ + tid] = s;
  }
}

// (CO,CI,3,3) fp32 -> f16 packed per MFMA A-fragment:
// dst[((cot*NK+ks)*64+lane)*8+j] = W[cot*16+(lane&15)][kk=ks*32+(lane>>4)*8+j]
__global__ void repack_f16(const float* __restrict__ src, f16* __restrict__ dst,
                           int CO, int CI, int CINH, int NK, int e0map) {
  const int n = (CO / 16) * NK * 64;
  for (int i = blockIdx.x * blockDim.x + threadIdx.x; i < n;
       i += gridDim.x * blockDim.x) {
    const int cot = i / (NK * 64);
    const int r = i - cot * NK * 64;
    const int ks = r >> 6, lph = r & 63;
    const int co = cot * 16 + (lph & 15);
    const int kbl = lph >> 4;
#pragma unroll
    for (int j = 0; j < 8; ++j) {
      const int kk = ks * 32 + kbl * 8 + j;
      const int k = kk / CINH, c = kk - k * CINH;
      int ci;
      if (e0map) ci = (c == 0) ? 0 : ((c >= 8 && c < 40) ? c - 7 : -1);
      else ci = (c < CI) ? c : -1;
      float wv = 0.f;
      if (ci >= 0) wv = src[((size_t)(co * CI + ci) * 3 + k) * 3 + 1];
      dst[(size_t)i * 8 + j] = (f16)wv;
    }
  }
}

__global__ void xcvt(const float* __restrict__ x, f16* __restrict__ xf, int n4) {
  for (int i = blockIdx.x * blockDim.x + threadIdx.x; i < n4;
       i += gridDim.x * blockDim.x) {
    const float4 v = ((const float4*)x)[i];
    f16x4 o;
    o[0] = (f16)v.x; o[1] = (f16)v.y; o[2] = (f16)v.z; o[3] = (f16)v.w;
    ((f16x4*)xf)[i] = o;
  }
}

extern "C" void kernel_launch(void* const* d_in, const int* in_sizes, int n_in,
                              void* d_out, int out_size, void* d_ws, size_t ws_size,
                              hipStream_t stream) {
  (void)in_sizes; (void)n_in; (void)out_size; (void)ws_size;
  const float* x = (const float*)d_in[0];
  const float* e0_wg = (const float*)d_in[1];
  const float* e0_bg = (const float*)d_in[2];
  const float* e0_wc = (const float*)d_in[3];
  const float* e0_bc = (const float*)d_in[4];
  const float* e1_wg = (const float*)d_in[5];
  const float* e1_bg = (const float*)d_in[6];
  const float* e1_wc = (const float*)d_in[7];
  const float* e1_bc = (const float*)d_in[8];
  const float* d0_wg = (const float*)d_in[9];
  const float* d0_bg = (const float*)d_in[10];
  const float* d0_wc = (const float*)d_in[11];
  const float* d0_bc = (const float*)d_in[12];
  const float* d1_wg = (const float*)d_in[13];
  const float* d1_bg = (const float*)d_in[14];
  const float* d1_wc = (const float*)d_in[15];
  const float* d1_bc = (const float*)d_in[16];
  const float* fw = (const float*)d_in[17];
  const float* fb = (const float*)d_in[18];
  float* out = (float*)d_out;

  char* p = (char*)d_ws;
  f16* y1g = (f16*)p;
  p += (size_t)B_ * T_ * 64 * 128 * 2;  // 104.86 MB
  f16* xf = (f16*)p;
  p += (size_t)B_ * T_ * F_ * 2;        // 1.64 MB
  auto aw = [&](int n) { f16* q = (f16*)p; p += (size_t)n * 2; return q; };
  f16* wgE0 = aw(64 * 192);
  f16* wcE0 = aw(32 * 192);
  f16* wgE1 = aw(128 * 288);
  f16* wcE1 = aw(64 * 288);
  f16* wgD0 = aw(128 * 384);
  f16* wcD0 = aw(64 * 384);
  f16* wgD1 = aw(64 * 288);
  f16* wcD1 = aw(32 * 288);

  auto rp = [&](const float* s, f16* d, int CO, int CI, int CINH, int e0m) {
    const int NK = 3 * CINH / 32;
    const int n = (CO / 16) * NK * 64;
    hipLaunchKernelGGL(repack_f16, dim3((n + 255) / 256), dim3(256), 0, stream,
                       s, d, CO, CI, CINH, NK, e0m);
  };
  rp(e0_wg, wgE0, 64, 33, 64, 1);
  rp(e0_wc, wcE0, 32, 33, 64, 1);
  rp(e1_wg, wgE1, 128, 96, 96, 0);
  rp(e1_wc, wcE1, 64, 96, 96, 0);
  rp(d0_wg, wgD0, 128, 128, 128, 0);
  rp(d0_wc, wcD0, 64, 128, 128, 0);
  rp(d1_wg, wgD1, 64, 96, 96, 0);
  rp(d1_wc, wcD1, 32, 96, 96, 0);
  hipLaunchKernelGGL(xcvt, dim3(200), dim3(1024), 0, stream, x, xf,
                     B_ * T_ * F_ / 4);

  hipFuncSetAttribute((const void*)ae_kernel,
                      hipFuncAttributeMaxDynamicSharedMemorySize, LDS_TOTAL);
  hipLaunchKernelGGL(ae_kernel, dim3(B_), dim3(1024), LDS_TOTAL, stream, xf, out,
                     wgE0, wcE0, e0_bg, e0_bc, wgE1, wcE1, e1_bg, e1_bc,
                     wgD0, wcD0, d0_bg, d0_bc, wgD1, wcD1, d1_bg, d1_bc,
                     fw, fb, y1g);
}

// Round 17
// 1843.039 us; speedup vs baseline: 1.1352x; 1.1352x over previous
//
#include <hip/hip_runtime.h>
#include <cstdint>
#include <cstddef>

// ConvGRU autoencoder, round 17: r12 (best, 1166us) + ISOLATED COT=2 retile
// for e1/d0 only. Each wave owns co-half cp=w&1 (2 cot for R, 2 for U) x
// f-group fg2=w>>1 (2 f-tiles): B-fragments reused across 2 co-tiles ->
// e1/d0 fragment LDS reads halve (72 b128/wave/t saved). Weights for those
// layers stream from global (idle pipe; FETCH at 1.6% peak) -- r8/r10's
// regressions were confounded by simultaneously ADDING weight-LDS reads;
// this version strictly reduces LDS traffic. Acc live-state unchanged
// (16 held regs, same as r12). e0/d1/schedule/cb-maps/ingest: r12 verbatim.

#define F_ 128
#define T_ 100
#define B_ 64
#define ROWSP 130
#define CBSTR (ROWSP * 8)    // f16 per cb
#define CBBYTE (ROWSP * 16)  // bytes per cb
#define AT_OFF 104448
#define LDS_TOTAL (AT_OFF + 28 * CBBYTE)  // 162688

typedef _Float16 f16;
typedef __attribute__((ext_vector_type(4))) float f32x4;
typedef __attribute__((ext_vector_type(8))) _Float16 f16x8;
typedef __attribute__((ext_vector_type(4))) _Float16 f16x4;

#define MFMA(a, b, c) __builtin_amdgcn_mfma_f32_16x16x32_f16(a, b, c, 0, 0, 0)

__device__ __forceinline__ float exp2_(float x) { return __builtin_amdgcn_exp2f(x); }
__device__ __forceinline__ float rcp_(float x) { return __builtin_amdgcn_rcpf(x); }

#define KSG (-1.442695041f)  // sigmoid: sig(v) = rcp(1+exp2(v*KSG))
#define KTH (-2.885390082f)  // tanh:    tanh(v) = 2*rcp(1+exp2(v*KTH)) - 1

// cb base per (layer, ks%NC3); fragment cb = base + kb (kb = lane>>4). (r9)
__host__ __device__ constexpr int cbA(int lid, int km) {
  return lid == 0 ? (km ? 4 : 0)
       : lid == 1 ? (1 + km * 4)
       : lid == 2 ? (km * 4)
                  : (8 + km * 4);
}
__host__ __device__ constexpr int cbB(int lid, int km) {
  return lid == 0 ? (km ? 17 : 13)
       : lid == 1 ? (km == 0 ? 1 : 14 + km * 4)
       : lid == 2 ? (km < 2 ? km * 4 : 12 + km * 4)
                  : (km < 2 ? 8 + km * 4 : 20);
}

// ---------------- FTW-tiled (e0, d1) -- r12 verbatim ----------------
template <int LID, int FTW, int NK, int NC3, bool WREG>
__device__ __forceinline__ void convA_f(
    const f16* __restrict__ rdB,
    const f16x8* __restrict__ aR, const f16x8* __restrict__ aU,
    const f16* __restrict__ gR, const f16* __restrict__ gU,
    f32x4* __restrict__ accR, f32x4* __restrict__ accU) {
#pragma unroll
  for (int j = 0; j < FTW; ++j) {
    accR[j] = (f32x4){0.f, 0.f, 0.f, 0.f};
    accU[j] = (f32x4){0.f, 0.f, 0.f, 0.f};
  }
#pragma unroll
  for (int ks = 0; ks < NK; ++ks) {
    const int k = ks / NC3, km = ks % NC3;
    const f16* fb = rdB + cbA(LID, km) * CBSTR + k * 8;
    f16x8 bf[FTW];
#pragma unroll
    for (int j = 0; j < FTW; ++j) bf[j] = *(const f16x8*)(fb + j * 128);
    f16x8 wr, wu;
    if constexpr (WREG) { wr = aR[ks]; wu = aU[ks]; }
    else {
      wr = *(const f16x8*)(gR + ks * 512);
      wu = *(const f16x8*)(gU + ks * 512);
    }
#pragma unroll
    for (int j = 0; j < FTW; ++j) accR[j] = MFMA(wr, bf[j], accR[j]);
#pragma unroll
    for (int j = 0; j < FTW; ++j) accU[j] = MFMA(wu, bf[j], accU[j]);
  }
}

template <int LID, int FTW, int NK, int NC3, bool CREG>
__device__ __forceinline__ void convB_f(
    const f16* __restrict__ rdB, const f16x8* __restrict__ cR,
    const f16* __restrict__ cW, f32x4* __restrict__ accC) {
#pragma unroll
  for (int j = 0; j < FTW; ++j) accC[j] = (f32x4){0.f, 0.f, 0.f, 0.f};
#pragma unroll
  for (int ks = 0; ks < NK; ++ks) {
    const int k = ks / NC3, km = ks % NC3;
    const f16* fb = rdB + cbB(LID, km) * CBSTR + k * 8;
    f16x8 bf[FTW];
#pragma unroll
    for (int j = 0; j < FTW; ++j) bf[j] = *(const f16x8*)(fb + j * 128);
    f16x8 wc;
    if constexpr (CREG) wc = cR[ks];
    else wc = *(const f16x8*)(cW + ks * 512);
#pragma unroll
    for (int j = 0; j < FTW; ++j) accC[j] = MFMA(wc, bf[j], accC[j]);
  }
}

template <int FTW, int RHCB>
__device__ __forceinline__ void postA_f(const f32x4* __restrict__ accR,
                                        const f32x4 bR,
                                        const f32x4* __restrict__ hreg,
                                        char* __restrict__ wrB) {
#pragma unroll
  for (int j = 0; j < FTW; ++j) {
    f16x4 rh;
#pragma unroll
    for (int q = 0; q < 4; ++q) {
      const float r = rcp_(1.0f + exp2_(fmaf(accR[j][q], KSG, bR[q])));
      rh[q] = (f16)(r * hreg[j][q]);
    }
    *(f16x4*)(wrB + RHCB * CBBYTE + j * 256) = rh;
  }
}

template <int FTW, int HCB, bool EMITY1>
__device__ __forceinline__ void postB_f(const f32x4* __restrict__ accU,
                                        const f32x4* __restrict__ accC,
                                        const f32x4 bU, const f32x4 bC,
                                        f32x4* __restrict__ hreg,
                                        char* __restrict__ wrB,
                                        f16* __restrict__ y1dst) {
#pragma unroll
  for (int j = 0; j < FTW; ++j) {
    f16x4 hh;
#pragma unroll
    for (int q = 0; q < 4; ++q) {
      const float u = rcp_(1.0f + exp2_(fmaf(accU[j][q], KSG, bU[q])));
      const float r = rcp_(1.0f + exp2_(fmaf(accC[j][q], KTH, bC[q])));
      const float h = hreg[j][q];
      const float s = fmaf(2.0f, r, -(1.0f + h));  // tanh(C) - h
      const float hn = fmaf(u, s, h);
      hreg[j][q] = hn;
      hh[q] = (f16)hn;
    }
    *(f16x4*)(wrB + HCB * CBBYTE + j * 256) = hh;
    if constexpr (EMITY1) *(f16x4*)(y1dst + j * 128) = hh;
  }
}

// ---------------- 2cot x 2ft tiled (e1, d0) ----------------
// acc arrays indexed [i*2+j]; weights flattened [i*NK+ks].
template <int LID, int NK, int NC3>
__device__ __forceinline__ void convA2_f(const f16* __restrict__ rdB,
                                         const f16x8* __restrict__ aR,
                                         const f16x8* __restrict__ aU,
                                         f32x4* __restrict__ accR,
                                         f32x4* __restrict__ accU) {
#pragma unroll
  for (int t = 0; t < 4; ++t) {
    accR[t] = (f32x4){0.f, 0.f, 0.f, 0.f};
    accU[t] = (f32x4){0.f, 0.f, 0.f, 0.f};
  }
#pragma unroll
  for (int ks = 0; ks < NK; ++ks) {
    const int k = ks / NC3, km = ks % NC3;
    const f16* fb = rdB + cbA(LID, km) * CBSTR + k * 8;
    const f16x8 b0 = *(const f16x8*)(fb);
    const f16x8 b1 = *(const f16x8*)(fb + 128);
#pragma unroll
    for (int i = 0; i < 2; ++i) {
      const f16x8 wr = aR[i * NK + ks];
      const f16x8 wu = aU[i * NK + ks];
      accR[i * 2 + 0] = MFMA(wr, b0, accR[i * 2 + 0]);
      accR[i * 2 + 1] = MFMA(wr, b1, accR[i * 2 + 1]);
      accU[i * 2 + 0] = MFMA(wu, b0, accU[i * 2 + 0]);
      accU[i * 2 + 1] = MFMA(wu, b1, accU[i * 2 + 1]);
    }
  }
}

template <int LID, int NK, int NC3, bool CREG>
__device__ __forceinline__ void convB2_f(const f16* __restrict__ rdB,
                                         const f16x8* __restrict__ cR,
                                         const f16* __restrict__ cW,
                                         f32x4* __restrict__ accC) {
#pragma unroll
  for (int t = 0; t < 4; ++t) accC[t] = (f32x4){0.f, 0.f, 0.f, 0.f};
#pragma unroll
  for (int ks = 0; ks < NK; ++ks) {
    const int k = ks / NC3, km = ks % NC3;
    const f16* fb = rdB + cbB(LID, km) * CBSTR + k * 8;
    const f16x8 b0 = *(const f16x8*)(fb);
    const f16x8 b1 = *(const f16x8*)(fb + 128);
#pragma unroll
    for (int i = 0; i < 2; ++i) {
      f16x8 wc;
      if constexpr (CREG) wc = cR[i * NK + ks];
      else wc = *(const f16x8*)(cW + (i * NK + ks) * 512);
      accC[i * 2 + 0] = MFMA(wc, b0, accC[i * 2 + 0]);
      accC[i * 2 + 1] = MFMA(wc, b1, accC[i * 2 + 1]);
    }
  }
}

template <int RHCB>
__device__ __forceinline__ void postA2_f(const f32x4* __restrict__ accR,
                                         const f32x4* __restrict__ bR2,
                                         const f32x4* __restrict__ hreg,
                                         char* __restrict__ wrB) {
#pragma unroll
  for (int i = 0; i < 2; ++i)
#pragma unroll
    for (int j = 0; j < 2; ++j) {
      const int t = i * 2 + j;
      f16x4 rh;
#pragma unroll
      for (int q = 0; q < 4; ++q) {
        const float r = rcp_(1.0f + exp2_(fmaf(accR[t][q], KSG, bR2[i][q])));
        rh[q] = (f16)(r * hreg[t][q]);
      }
      *(f16x4*)(wrB + RHCB * CBBYTE + i * 2 * CBBYTE + j * 256) = rh;
    }
}

template <int HCB, bool EMITY1>
__device__ __forceinline__ void postB2_f(const f32x4* __restrict__ accU,
                                         const f32x4* __restrict__ accC,
                                         const f32x4* __restrict__ bU2,
                                         const f32x4* __restrict__ bC2,
                                         f32x4* __restrict__ hreg,
                                         char* __restrict__ wrB,
                                         f16* __restrict__ y1dst) {
#pragma unroll
  for (int i = 0; i < 2; ++i)
#pragma unroll
    for (int j = 0; j < 2; ++j) {
      const int t = i * 2 + j;
      f16x4 hh;
#pragma unroll
      for (int q = 0; q < 4; ++q) {
        const float u = rcp_(1.0f + exp2_(fmaf(accU[t][q], KSG, bU2[i][q])));
        const float r = rcp_(1.0f + exp2_(fmaf(accC[t][q], KTH, bC2[i][q])));
        const float h = hreg[t][q];
        const float s = fmaf(2.0f, r, -(1.0f + h));
        const float hn = fmaf(u, s, h);
        hreg[t][q] = hn;
        hh[q] = (f16)hn;
      }
      *(f16x4*)(wrB + HCB * CBBYTE + i * 2 * CBBYTE + j * 256) = hh;
      if constexpr (EMITY1) *(f16x4*)(y1dst + i * 2048 + j * 128) = hh;
    }
}

__global__ __launch_bounds__(512, 1) void ae_kernel(
    const f16* __restrict__ xf, float* __restrict__ out,
    const f16* __restrict__ wgE0, const f16* __restrict__ wcE0,
    const float* __restrict__ bgE0, const float* __restrict__ bcE0,
    const f16* __restrict__ wgE1, const f16* __restrict__ wcE1,
    const float* __restrict__ bgE1, const float* __restrict__ bcE1,
    const f16* __restrict__ wgD0, const f16* __restrict__ wcD0,
    const float* __restrict__ bgD0, const float* __restrict__ bcD0,
    const f16* __restrict__ wgD1, const f16* __restrict__ wcD1,
    const float* __restrict__ bgD1, const float* __restrict__ bcD1,
    const float* __restrict__ fw, const float* __restrict__ fb,
    f16* __restrict__ y1g) {
  extern __shared__ char smem[];
  f16* aT = (f16*)(smem + AT_OFF);
  char* atB = smem + AT_OFF;
  const int tid = threadIdx.x, b = blockIdx.x;
  const int w = tid >> 6, l = tid & 63;
  const int m16 = l & 15, kb = l >> 4;
  const int cp = w & 1, fg2 = w >> 1;  // co-half and f-group (32 f)

  // zero aT (28 cb)
  for (int i = tid; i < 28 * CBBYTE / 16; i += 512)
    ((f32x4*)atB)[i] = (f32x4){0.f, 0.f, 0.f, 0.f};
  // encoder LDS weights: wgE0@0 (24576 B), wcE0@24576 (12288 B)
  for (int i = tid; i < 1536; i += 512)
    ((f16x8*)(smem + 0))[i] = ((const f16x8*)wgE0)[i];
  for (int i = tid; i < 768; i += 512)
    ((f16x8*)(smem + 24576))[i] = ((const f16x8*)wcE0)[i];

  // e1 weights: 2 cot slices per wave (compiler streams from L2)
  f16x8 aR1[18], aU1[18], cE1[18];
#pragma unroll
  for (int i = 0; i < 2; ++i)
#pragma unroll
    for (int ks = 0; ks < 9; ++ks) {
      aR1[i * 9 + ks] = ((const f16x8*)wgE1)[((2 * cp + i) * 9 + ks) * 64 + l];
      aU1[i * 9 + ks] =
          ((const f16x8*)wgE1)[((2 * cp + i + 4) * 9 + ks) * 64 + l];
      cE1[i * 9 + ks] = ((const f16x8*)wcE1)[((2 * cp + i) * 9 + ks) * 64 + l];
    }
  // biases (scale folded); co per cot
  const int kb4 = kb * 4;
  const int co2 = cp * 16 + kb4;
  const int coA = (2 * cp) * 16 + kb4, coB = (2 * cp + 1) * 16 + kb4;
  f32x4 bRe0, bUe0, bCe0, bRe1[2], bUe1[2], bCe1[2];
#pragma unroll
  for (int q = 0; q < 4; ++q) {
    bRe0[q] = bgE0[co2 + q] * KSG;
    bUe0[q] = bgE0[32 + co2 + q] * KSG;
    bCe0[q] = bcE0[co2 + q] * KTH;
    bRe1[0][q] = bgE1[coA + q] * KSG;
    bRe1[1][q] = bgE1[coB + q] * KSG;
    bUe1[0][q] = bgE1[64 + coA + q] * KSG;
    bUe1[1][q] = bgE1[64 + coB + q] * KSG;
    bCe1[0][q] = bcE1[coA + q] * KTH;
    bCe1[1][q] = bcE1[coB + q] * KTH;
  }
  // per-thread LDS bases
  const int rowb = (fg2 * 32 + m16 + 1) * 16 + (kb & 1) * 8;
  const f16* rdB = aT + kb * CBSTR + (fg2 * 32 + m16) * 8;
  char* wrB2 = atB + (cp * 2 + (kb >> 1)) * CBBYTE + rowb;
  char* wrB4 = atB + (4 * cp + (kb >> 1)) * CBBYTE + rowb;
  f16* y1t = y1g + (size_t)b * T_ * 8192 +
             ((4 * cp + (kb >> 1)) * 128 + fg2 * 32 + m16) * 8 + (kb & 1) * 4;
  const f16* gE0R = (const f16*)(smem + 0) + (cp * 6) * 512 + l * 8;
  const f16* gE0U = (const f16*)(smem + 0) + ((2 + cp) * 6) * 512 + l * 8;
  const f16* cE0l = (const f16*)(smem + 24576) + (cp * 6) * 512 + l * 8;

  f32x4 h0r[2], h1r[4];
#pragma unroll
  for (int j = 0; j < 2; ++j) h0r[j] = (f32x4){0.f, 0.f, 0.f, 0.f};
#pragma unroll
  for (int j = 0; j < 4; ++j) h1r[j] = (f32x4){0.f, 0.f, 0.f, 0.f};
  __syncthreads();

  // ================= encoder (4 windows/t) =================
  const f16* xb = xf + (size_t)b * T_ * F_;
  if (tid < F_) {  // ingest x(0)
    const f16 v = xb[tid];
    aT[(tid + 1) * 8] = v;
    aT[13 * CBSTR + (tid + 1) * 8] = v;
  }
  __syncthreads();
  for (int t = 0; t < T_; ++t) {
    // W2: e0 convA + postA ; issue x(t+1) -> reg
    f32x4 aR0g[2], aU0g[2];
    convA_f<0, 2, 6, 2, false>(rdB, nullptr, nullptr, gE0R, gE0U, aR0g, aU0g);
    f16 xpre = (f16)0.f;
    if (t + 1 < T_ && tid < F_) xpre = xb[(t + 1) * F_ + tid];
    postA_f<2, 14>(aR0g, bRe0, h0r, wrB2);
    __syncthreads();
    // W3: e0 convB + postB
    f32x4 aC0[2];
    convB_f<0, 2, 6, 2, false>(rdB, nullptr, cE0l, aC0);
    postB_f<2, 1, false>(aU0g, aC0, bUe0, bCe0, h0r, wrB2, nullptr);
    __syncthreads();
    // W4: e1 convA + postA ; write x(t+1) (cb0/13 not read here)
    f32x4 aR1g[4], aU1g[4];
    convA2_f<1, 9, 3>(rdB, aR1, aU1, aR1g, aU1g);
    if (t + 1 < T_ && tid < F_) {
      aT[(tid + 1) * 8] = xpre;
      aT[13 * CBSTR + (tid + 1) * 8] = xpre;
    }
    postA2_f<18>(aR1g, bRe1, h1r, wrB4);
    __syncthreads();
    // W5: e1 convB + postB (+ y1 emit)
    f32x4 aC1[4];
    convB2_f<1, 9, 3, true>(rdB, cE1, nullptr, aC1);
    postB2_f<5, true>(aU1g, aC1, bUe1, bCe1, h1r, wrB4,
                      y1t + (size_t)t * 8192);
    __syncthreads();
  }

  // ================= transition to decoder =================
  {  // hd0 init (cb8-15, from h1r [i][j] tiling); hd1 init (cb16-19, h0r)
#pragma unroll
    for (int i = 0; i < 2; ++i)
#pragma unroll
      for (int j = 0; j < 2; ++j) {
        f16x4 hh;
#pragma unroll
        for (int q = 0; q < 4; ++q) hh[q] = (f16)h1r[i * 2 + j][q];
        *(f16x4*)(wrB4 + 8 * CBBYTE + i * 2 * CBBYTE + j * 256) = hh;
      }
#pragma unroll
    for (int j = 0; j < 2; ++j) {
      f16x4 hh;
#pragma unroll
      for (int q = 0; q < 4; ++q) hh[q] = (f16)h0r[j][q];
      *(f16x4*)(wrB2 + 16 * CBBYTE + j * 256) = hh;
    }
  }
  // dec LDS weights: wcD0@0 (49152 B), wgD1@49152 (36864 B), wcD1@86016
  for (int i = tid; i < 3072; i += 512)
    ((f16x8*)(smem + 0))[i] = ((const f16x8*)wcD0)[i];
  for (int i = tid; i < 2304; i += 512)
    ((f16x8*)(smem + 49152))[i] = ((const f16x8*)wgD1)[i];
  for (int i = tid; i < 1152; i += 512)
    ((f16x8*)(smem + 86016))[i] = ((const f16x8*)wcD1)[i];
  // d0 gates: 2 cot slices (streamed)
  f16x8 aR0[24], aU0[24];
#pragma unroll
  for (int i = 0; i < 2; ++i)
#pragma unroll
    for (int ks = 0; ks < 12; ++ks) {
      aR0[i * 12 + ks] =
          ((const f16x8*)wgD0)[((2 * cp + i) * 12 + ks) * 64 + l];
      aU0[i * 12 + ks] =
          ((const f16x8*)wgD0)[((2 * cp + i + 4) * 12 + ks) * 64 + l];
    }
  // dec biases
  f32x4 bRd0[2], bUd0[2], bCd0[2], bRd1, bUd1, bCd1;
#pragma unroll
  for (int q = 0; q < 4; ++q) {
    bRd0[0][q] = bgD0[coA + q] * KSG;
    bRd0[1][q] = bgD0[coB + q] * KSG;
    bUd0[0][q] = bgD0[64 + coA + q] * KSG;
    bUd0[1][q] = bgD0[64 + coB + q] * KSG;
    bCd0[0][q] = bcD0[coA + q] * KTH;
    bCd0[1][q] = bcD0[coB + q] * KTH;
    bRd1[q] = bgD1[co2 + q] * KSG;
    bUd1[q] = bgD1[32 + co2 + q] * KSG;
    bCd1[q] = bcD1[co2 + q] * KTH;
  }
  const f16* cD0l = (const f16*)(smem + 0) + (2 * cp * 12) * 512 + l * 8;
  const f16* gD1R = (const f16*)(smem + 49152) + (cp * 9) * 512 + l * 8;
  const f16* gD1U = (const f16*)(smem + 49152) + ((2 + cp) * 9) * 512 + l * 8;
  const f16* cD1l = (const f16*)(smem + 86016) + (cp * 9) * 512 + l * 8;
  const float fb0 = fb[0];
  __syncthreads();
  {  // ingest y1(0)
    const f16x8* src = (const f16x8*)(y1g + (size_t)b * T_ * 8192);
#pragma unroll
    for (int k2 = 0; k2 < 2; ++k2) {
      const int i = tid + k2 * 512;
      *(f16x8*)&aT[(i >> 7) * CBSTR + ((i & 127) + 1) * 8] = src[i];
    }
  }
  __syncthreads();

  // ================= decoder (4 windows/t; out shifted 1 window) ===========
  for (int t = 0; t < T_; ++t) {
    // W2: d0 convA + postA ; out(t-1) (cb16-19 stable) ; issue y1(t+1)
    f32x4 aRd0[4], aUd0[4];
    convA2_f<2, 12, 4>(rdB, aR0, aU0, aRd0, aUd0);
    if (t >= 1 && tid < F_) {
      float s = fb0;
#pragma unroll
      for (int cb = 0; cb < 4; ++cb) {
        const f16x8 h8 = *(const f16x8*)&aT[(16 + cb) * CBSTR + (tid + 1) * 8];
#pragma unroll
        for (int q = 0; q < 8; ++q) s = fmaf(fw[cb * 8 + q], (float)h8[q], s);
      }
      out[((size_t)b * T_ + (t - 1)) * F_ + tid] = s;
    }
    f16x8 yp0 = {}, yp1 = {};
    if (t + 1 < T_) {
      const f16x8* src = (const f16x8*)(y1g + ((size_t)b * T_ + t + 1) * 8192);
      yp0 = src[tid];
      yp1 = src[tid + 512];
    }
    postA2_f<20>(aRd0, bRd0, h1r, wrB4);
    __syncthreads();
    // W3: d0 convB (cand from LDS, 2 slices) + postB
    f32x4 aCd0[4];
    convB2_f<2, 12, 4, false>(rdB, nullptr, cD0l, aCd0);
    postB2_f<8, false>(aUd0, aCd0, bUd0, bCd0, h1r, wrB4, nullptr);
    __syncthreads();
    // W4: d1 convA + postA ; write y1(t+1) -> cb0-7 (not read here)
    f32x4 aRd1[2], aUd1[2];
    convA_f<3, 2, 9, 3, false>(rdB, nullptr, nullptr, gD1R, gD1U, aRd1, aUd1);
    if (t + 1 < T_) {
      const int i0 = tid, i1 = tid + 512;
      *(f16x8*)&aT[(i0 >> 7) * CBSTR + ((i0 & 127) + 1) * 8] = yp0;
      *(f16x8*)&aT[(i1 >> 7) * CBSTR + ((i1 & 127) + 1) * 8] = yp1;
    }
    postA_f<2, 20>(aRd1, bRd1, h0r, wrB2);
    __syncthreads();
    // W5: d1 convB + postB
    f32x4 aCd1[2];
    convB_f<3, 2, 9, 3, false>(rdB, nullptr, cD1l, aCd1);
    postB_f<2, 16, false>(aUd1, aCd1, bUd1, bCd1, h0r, wrB2, nullptr);
    __syncthreads();
  }
  if (tid < F_) {  // epilogue: out(T-1)
    float s = fb0;
#pragma unroll
    for (int cb = 0; cb < 4; ++cb) {
      const f16x8 h8 = *(const f16x8*)&aT[(16 + cb) * CBSTR + (tid + 1) * 8];
#pragma unroll
      for (int q = 0; q < 8; ++q) s = fmaf(fw[cb * 8 + q], (float)h8[q], s);
    }
    out[((size_t)b * T_ + (T_ - 1)) * F_ + tid] = s;
  }
}

// (CO,CI,3,3) fp32 -> f16 packed per MFMA A-fragment:
// dst[((cot*NK+ks)*64+lane)*8+j] = W[cot*16+(lane&15)][kk=ks*32+(lane>>4)*8+j]
__global__ void repack_f16(const float* __restrict__ src, f16* __restrict__ dst,
                           int CO, int CI, int CINH, int NK, int e0map) {
  const int n = (CO / 16) * NK * 64;
  for (int i = blockIdx.x * blockDim.x + threadIdx.x; i < n;
       i += gridDim.x * blockDim.x) {
    const int cot = i / (NK * 64);
    const int r = i - cot * NK * 64;
    const int ks = r >> 6, lph = r & 63;
    const int co = cot * 16 + (lph & 15);
    const int kbl = lph >> 4;
#pragma unroll
    for (int j = 0; j < 8; ++j) {
      const int kk = ks * 32 + kbl * 8 + j;
      const int k = kk / CINH, c = kk - k * CINH;
      int ci;
      if (e0map) ci = (c == 0) ? 0 : ((c >= 8 && c < 40) ? c - 7 : -1);
      else ci = (c < CI) ? c : -1;
      float wv = 0.f;
      if (ci >= 0) wv = src[((size_t)(co * CI + ci) * 3 + k) * 3 + 1];
      dst[(size_t)i * 8 + j] = (f16)wv;
    }
  }
}

__global__ void xcvt(const float* __restrict__ x, f16* __restrict__ xf, int n4) {
  for (int i = blockIdx.x * blockDim.x + threadIdx.x; i < n4;
       i += gridDim.x * blockDim.x) {
    const float4 v = ((const float4*)x)[i];
    f16x4 o;
    o[0] = (f16)v.x; o[1] = (f16)v.y; o[2] = (f16)v.z; o[3] = (f16)v.w;
    ((f16x4*)xf)[i] = o;
  }
}

extern "C" void kernel_launch(void* const* d_in, const int* in_sizes, int n_in,
                              void* d_out, int out_size, void* d_ws, size_t ws_size,
                              hipStream_t stream) {
  (void)in_sizes; (void)n_in; (void)out_size; (void)ws_size;
  const float* x = (const float*)d_in[0];
  const float* e0_wg = (const float*)d_in[1];
  const float* e0_bg = (const float*)d_in[2];
  const float* e0_wc = (const float*)d_in[3];
  const float* e0_bc = (const float*)d_in[4];
  const float* e1_wg = (const float*)d_in[5];
  const float* e1_bg = (const float*)d_in[6];
  const float* e1_wc = (const float*)d_in[7];
  const float* e1_bc = (const float*)d_in[8];
  const float* d0_wg = (const float*)d_in[9];
  const float* d0_bg = (const float*)d_in[10];
  const float* d0_wc = (const float*)d_in[11];
  const float* d0_bc = (const float*)d_in[12];
  const float* d1_wg = (const float*)d_in[13];
  const float* d1_bg = (const float*)d_in[14];
  const float* d1_wc = (const float*)d_in[15];
  const float* d1_bc = (const float*)d_in[16];
  const float* fw = (const float*)d_in[17];
  const float* fb = (const float*)d_in[18];
  float* out = (float*)d_out;

  char* p = (char*)d_ws;
  f16* y1g = (f16*)p;
  p += (size_t)B_ * T_ * 64 * 128 * 2;  // 104.86 MB
  f16* xf = (f16*)p;
  p += (size_t)B_ * T_ * F_ * 2;        // 1.64 MB
  auto aw = [&](int n) { f16* q = (f16*)p; p += (size_t)n * 2; return q; };
  f16* wgE0 = aw(64 * 192);
  f16* wcE0 = aw(32 * 192);
  f16* wgE1 = aw(128 * 288);
  f16* wcE1 = aw(64 * 288);
  f16* wgD0 = aw(128 * 384);
  f16* wcD0 = aw(64 * 384);
  f16* wgD1 = aw(64 * 288);
  f16* wcD1 = aw(32 * 288);

  auto rp = [&](const float* s, f16* d, int CO, int CI, int CINH, int e0m) {
    const int NK = 3 * CINH / 32;
    const int n = (CO / 16) * NK * 64;
    hipLaunchKernelGGL(repack_f16, dim3((n + 255) / 256), dim3(256), 0, stream,
                       s, d, CO, CI, CINH, NK, e0m);
  };
  rp(e0_wg, wgE0, 64, 33, 64, 1);
  rp(e0_wc, wcE0, 32, 33, 64, 1);
  rp(e1_wg, wgE1, 128, 96, 96, 0);
  rp(e1_wc, wcE1, 64, 96, 96, 0);
  rp(d0_wg, wgD0, 128, 128, 128, 0);
  rp(d0_wc, wcD0, 64, 128, 128, 0);
  rp(d1_wg, wgD1, 64, 96, 96, 0);
  rp(d1_wc, wcD1, 32, 96, 96, 0);
  hipLaunchKernelGGL(xcvt, dim3(200), dim3(1024), 0, stream, x, xf,
                     B_ * T_ * F_ / 4);

  hipFuncSetAttribute((const void*)ae_kernel,
                      hipFuncAttributeMaxDynamicSharedMemorySize, LDS_TOTAL);
  hipLaunchKernelGGL(ae_kernel, dim3(B_), dim3(512), LDS_TOTAL, stream, xf, out,
                     wgE0, wcE0, e0_bg, e0_bc, wgE1, wcE1, e1_bg, e1_bc,
                     wgD0, wcD0, d0_bg, d0_bc, wgD1, wcD1, d1_bg, d1_bc,
                     fw, fb, y1g);
}

// Round 18
// 1142.916 us; speedup vs baseline: 1.8307x; 1.6126x over previous
//
#include <hip/hip_runtime.h>
#include <cstdint>
#include <cstddef>

// ConvGRU autoencoder, round 18: REVERT to r12 (best measured, 1166us) +
// merged prologue (8 repacks + xcvt -> 1 prep_kernel; saves ~8 graph-node
// gaps). ae_kernel is r12 verbatim:
//  - 1 block/batch (512 thr), 4 windows/t, async x/y1 ingest (issue in W2,
//    LDS-write in W4), dec out shifted one window.
//  - r9-measured weight placement: e0/d1 gates+cand and d0 cand in LDS;
//    e1 gates+cand and d0 gates streamed from L2 by the compiler.
// Structural constraints (evidence r5..r17): cross-WG per-step sync ~9us
// (prohibitive); every variant adding live register state across barriers
// or widening per-wave weight streams regressed; 64/256 CUs is inherent
// to B=64 independent recurrent chains.

#define F_ 128
#define T_ 100
#define B_ 64
#define ROWSP 130
#define CBSTR (ROWSP * 8)    // f16 per cb
#define CBBYTE (ROWSP * 16)  // bytes per cb
#define AT_OFF 104448
#define LDS_TOTAL (AT_OFF + 28 * CBBYTE)  // 162688

typedef _Float16 f16;
typedef __attribute__((ext_vector_type(4))) float f32x4;
typedef __attribute__((ext_vector_type(8))) _Float16 f16x8;
typedef __attribute__((ext_vector_type(4))) _Float16 f16x4;

#define MFMA(a, b, c) __builtin_amdgcn_mfma_f32_16x16x32_f16(a, b, c, 0, 0, 0)

__device__ __forceinline__ float exp2_(float x) { return __builtin_amdgcn_exp2f(x); }
__device__ __forceinline__ float rcp_(float x) { return __builtin_amdgcn_rcpf(x); }

#define KSG (-1.442695041f)  // sigmoid: sig(v) = rcp(1+exp2(v*KSG))
#define KTH (-2.885390082f)  // tanh:    tanh(v) = 2*rcp(1+exp2(v*KTH)) - 1

// cb base per (layer, ks%NC3); fragment cb = base + kb (kb = lane>>4). (r9)
__host__ __device__ constexpr int cbA(int lid, int km) {
  return lid == 0 ? (km ? 4 : 0)
       : lid == 1 ? (1 + km * 4)
       : lid == 2 ? (km * 4)
                  : (8 + km * 4);
}
__host__ __device__ constexpr int cbB(int lid, int km) {
  return lid == 0 ? (km ? 17 : 13)
       : lid == 1 ? (km == 0 ? 1 : 14 + km * 4)
       : lid == 2 ? (km < 2 ? km * 4 : 12 + km * 4)
                  : (km < 2 ? 8 + km * 4 : 20);
}

// Gate convs (R,U) over [x ; h]. Weights from regs (WREG) or LDS.
template <int LID, int FTW, int NK, int NC3, bool WREG>
__device__ __forceinline__ void convA_f(
    const f16* __restrict__ rdB,
    const f16x8* __restrict__ aR, const f16x8* __restrict__ aU,
    const f16* __restrict__ gR, const f16* __restrict__ gU,
    f32x4* __restrict__ accR, f32x4* __restrict__ accU) {
#pragma unroll
  for (int j = 0; j < FTW; ++j) {
    accR[j] = (f32x4){0.f, 0.f, 0.f, 0.f};
    accU[j] = (f32x4){0.f, 0.f, 0.f, 0.f};
  }
#pragma unroll
  for (int ks = 0; ks < NK; ++ks) {
    const int k = ks / NC3, km = ks % NC3;
    const f16* fb = rdB + cbA(LID, km) * CBSTR + k * 8;
    f16x8 bf[FTW];
#pragma unroll
    for (int j = 0; j < FTW; ++j) bf[j] = *(const f16x8*)(fb + j * 128);
    f16x8 wr, wu;
    if constexpr (WREG) { wr = aR[ks]; wu = aU[ks]; }
    else {
      wr = *(const f16x8*)(gR + ks * 512);
      wu = *(const f16x8*)(gU + ks * 512);
    }
#pragma unroll
    for (int j = 0; j < FTW; ++j) accR[j] = MFMA(wr, bf[j], accR[j]);
#pragma unroll
    for (int j = 0; j < FTW; ++j) accU[j] = MFMA(wu, bf[j], accU[j]);
  }
}

// Candidate conv over [x ; r*h]. Weights from regs (CREG) or LDS.
template <int LID, int FTW, int NK, int NC3, bool CREG>
__device__ __forceinline__ void convB_f(
    const f16* __restrict__ rdB, const f16x8* __restrict__ cR,
    const f16* __restrict__ cW, f32x4* __restrict__ accC) {
#pragma unroll
  for (int j = 0; j < FTW; ++j) accC[j] = (f32x4){0.f, 0.f, 0.f, 0.f};
#pragma unroll
  for (int ks = 0; ks < NK; ++ks) {
    const int k = ks / NC3, km = ks % NC3;
    const f16* fb = rdB + cbB(LID, km) * CBSTR + k * 8;
    f16x8 bf[FTW];
#pragma unroll
    for (int j = 0; j < FTW; ++j) bf[j] = *(const f16x8*)(fb + j * 128);
    f16x8 wc;
    if constexpr (CREG) wc = cR[ks];
    else wc = *(const f16x8*)(cW + ks * 512);
#pragma unroll
    for (int j = 0; j < FTW; ++j) accC[j] = MFMA(wc, bf[j], accC[j]);
  }
}

// rh = sigm(R)*h into cb RHCB (relative to wrB's base cb).
template <int FTW, int RHCB>
__device__ __forceinline__ void postA_f(const f32x4* __restrict__ accR,
                                        const f32x4 bR,
                                        const f32x4* __restrict__ hreg,
                                        char* __restrict__ wrB) {
#pragma unroll
  for (int j = 0; j < FTW; ++j) {
    f16x4 rh;
#pragma unroll
    for (int q = 0; q < 4; ++q) {
      const float r = rcp_(1.0f + exp2_(fmaf(accR[j][q], KSG, bR[q])));
      rh[q] = (f16)(r * hreg[j][q]);
    }
    *(f16x4*)(wrB + RHCB * CBBYTE + j * 256) = rh;
  }
}

// u = sigm(U); h = h + u*(tanh(C)-h); write h cb (+ y1 emit).
template <int FTW, int HCB, bool EMITY1>
__device__ __forceinline__ void postB_f(const f32x4* __restrict__ accU,
                                        const f32x4* __restrict__ accC,
                                        const f32x4 bU, const f32x4 bC,
                                        f32x4* __restrict__ hreg,
                                        char* __restrict__ wrB,
                                        f16* __restrict__ y1dst) {
#pragma unroll
  for (int j = 0; j < FTW; ++j) {
    f16x4 hh;
#pragma unroll
    for (int q = 0; q < 4; ++q) {
      const float u = rcp_(1.0f + exp2_(fmaf(accU[j][q], KSG, bU[q])));
      const float r = rcp_(1.0f + exp2_(fmaf(accC[j][q], KTH, bC[q])));
      const float h = hreg[j][q];
      const float s = fmaf(2.0f, r, -(1.0f + h));  // tanh(C) - h
      const float hn = fmaf(u, s, h);
      hreg[j][q] = hn;
      hh[q] = (f16)hn;
    }
    *(f16x4*)(wrB + HCB * CBBYTE + j * 256) = hh;
    if constexpr (EMITY1) *(f16x4*)(y1dst + j * 128) = hh;
  }
}

__global__ __launch_bounds__(512, 1) void ae_kernel(
    const f16* __restrict__ xf, float* __restrict__ out,
    const f16* __restrict__ wgE0, const f16* __restrict__ wcE0,
    const float* __restrict__ bgE0, const float* __restrict__ bcE0,
    const f16* __restrict__ wgE1, const f16* __restrict__ wcE1,
    const float* __restrict__ bgE1, const float* __restrict__ bcE1,
    const f16* __restrict__ wgD0, const f16* __restrict__ wcD0,
    const float* __restrict__ bgD0, const float* __restrict__ bcD0,
    const f16* __restrict__ wgD1, const f16* __restrict__ wcD1,
    const float* __restrict__ bgD1, const float* __restrict__ bcD1,
    const float* __restrict__ fw, const float* __restrict__ fb,
    f16* __restrict__ y1g) {
  extern __shared__ char smem[];
  f16* aT = (f16*)(smem + AT_OFF);
  const int tid = threadIdx.x, b = blockIdx.x;
  const int w = tid >> 6, l = tid & 63;
  const int m16 = l & 15, kb = l >> 4;

  // zero aT (28 cb)
  for (int i = tid; i < 28 * CBBYTE / 16; i += 512)
    ((f32x4*)(smem + AT_OFF))[i] = (f32x4){0.f, 0.f, 0.f, 0.f};
  // encoder LDS weights: wgE0@0 (24576 B), wcE0@24576 (12288 B)
  for (int i = tid; i < 1536; i += 512)
    ((f16x8*)(smem + 0))[i] = ((const f16x8*)wgE0)[i];
  for (int i = tid; i < 768; i += 512)
    ((f16x8*)(smem + 24576))[i] = ((const f16x8*)wcE0)[i];

  // e1 gate + cand weights (compiler streams from L2; measured-best, r9)
  const int cot2 = w & 1, cot4 = w & 3;
  f16x8 aR1[9], aU1[9], cE1[9];
#pragma unroll
  for (int ks = 0; ks < 9; ++ks) {
    aR1[ks] = ((const f16x8*)wgE1)[(cot4 * 9 + ks) * 64 + l];
    aU1[ks] = ((const f16x8*)wgE1)[((cot4 + 4) * 9 + ks) * 64 + l];
    cE1[ks] = ((const f16x8*)wcE1)[(cot4 * 9 + ks) * 64 + l];
  }
  // enc biases (scale folded)
  const int co2 = cot2 * 16 + kb * 4;
  const int co4 = cot4 * 16 + kb * 4;
  f32x4 bRe0, bUe0, bCe0, bRe1, bUe1, bCe1;
#pragma unroll
  for (int q = 0; q < 4; ++q) {
    bRe0[q] = bgE0[co2 + q] * KSG;
    bUe0[q] = bgE0[32 + co2 + q] * KSG;
    bCe0[q] = bcE0[co2 + q] * KTH;
    bRe1[q] = bgE1[co4 + q] * KSG;
    bUe1[q] = bgE1[64 + co4 + q] * KSG;
    bCe1[q] = bcE1[co4 + q] * KTH;
  }
  // per-thread LDS bases (r9)
  const int ft2 = (w >> 1) * 2, ft4 = (w >> 2) * 4;
  const f16* rdB2 = aT + kb * CBSTR + (ft2 * 16 + m16) * 8;
  const f16* rdB4 = aT + kb * CBSTR + (ft4 * 16 + m16) * 8;
  char* wrB2 = (char*)aT + (cot2 * 2 + (kb >> 1)) * CBBYTE +
               (ft2 * 16 + m16 + 1) * 16 + (kb & 1) * 8;
  char* wrB4 = (char*)aT + (cot4 * 2 + (kb >> 1)) * CBBYTE +
               (ft4 * 16 + m16 + 1) * 16 + (kb & 1) * 8;
  f16* y1t = y1g + (size_t)b * T_ * 8192 +
             ((cot4 * 2 + (kb >> 1)) * 128 + ft4 * 16 + m16) * 8 + (kb & 1) * 4;
  const f16* gE0R = (const f16*)(smem + 0) + (cot2 * 6) * 512 + l * 8;
  const f16* gE0U = (const f16*)(smem + 0) + ((2 + cot2) * 6) * 512 + l * 8;
  const f16* cE0l = (const f16*)(smem + 24576) + (cot2 * 6) * 512 + l * 8;

  f32x4 h0r[2], h1r[4];
#pragma unroll
  for (int j = 0; j < 2; ++j) h0r[j] = (f32x4){0.f, 0.f, 0.f, 0.f};
#pragma unroll
  for (int j = 0; j < 4; ++j) h1r[j] = (f32x4){0.f, 0.f, 0.f, 0.f};
  __syncthreads();

  // ================= encoder (4 windows/t) =================
  const f16* xb = xf + (size_t)b * T_ * F_;
  if (tid < F_) {  // ingest x(0)
    const f16 v = xb[tid];
    aT[(tid + 1) * 8] = v;
    aT[13 * CBSTR + (tid + 1) * 8] = v;
  }
  __syncthreads();
  for (int t = 0; t < T_; ++t) {
    // W2: e0 convA + postA ; issue x(t+1) -> reg
    f32x4 aR0g[2], aU0g[2];
    convA_f<0, 2, 6, 2, false>(rdB2, nullptr, nullptr, gE0R, gE0U, aR0g, aU0g);
    f16 xpre = (f16)0.f;
    if (t + 1 < T_ && tid < F_) xpre = xb[(t + 1) * F_ + tid];
    postA_f<2, 14>(aR0g, bRe0, h0r, wrB2);
    __syncthreads();
    // W3: e0 convB + postB
    f32x4 aC0[2];
    convB_f<0, 2, 6, 2, false>(rdB2, nullptr, cE0l, aC0);
    postB_f<2, 1, false>(aU0g, aC0, bUe0, bCe0, h0r, wrB2, nullptr);
    __syncthreads();
    // W4: e1 convA + postA ; write x(t+1) (cb0/13 not read here)
    f32x4 aR1g[4], aU1g[4];
    convA_f<1, 4, 9, 3, true>(rdB4, aR1, aU1, nullptr, nullptr, aR1g, aU1g);
    if (t + 1 < T_ && tid < F_) {
      aT[(tid + 1) * 8] = xpre;
      aT[13 * CBSTR + (tid + 1) * 8] = xpre;
    }
    postA_f<4, 18>(aR1g, bRe1, h1r, wrB4);
    __syncthreads();
    // W5: e1 convB + postB (+ y1 emit)
    f32x4 aC1[4];
    convB_f<1, 4, 9, 3, true>(rdB4, cE1, nullptr, aC1);
    postB_f<4, 5, true>(aU1g, aC1, bUe1, bCe1, h1r, wrB4,
                        y1t + (size_t)t * 8192);
    __syncthreads();
  }

  // ================= transition to decoder =================
  {  // hd0 init cols 64+ (= cb8-15, from h1r); hd1 init cols 128+ (cb16-19)
#pragma unroll
    for (int j = 0; j < 4; ++j) {
      f16x4 hh;
#pragma unroll
      for (int q = 0; q < 4; ++q) hh[q] = (f16)h1r[j][q];
      *(f16x4*)(wrB4 + 8 * CBBYTE + j * 256) = hh;
    }
#pragma unroll
    for (int j = 0; j < 2; ++j) {
      f16x4 hh;
#pragma unroll
      for (int q = 0; q < 4; ++q) hh[q] = (f16)h0r[j][q];
      *(f16x4*)(wrB2 + 16 * CBBYTE + j * 256) = hh;
    }
  }
  // dec LDS weights: wcD0@0 (49152 B), wgD1@49152 (36864 B), wcD1@86016
  for (int i = tid; i < 3072; i += 512)
    ((f16x8*)(smem + 0))[i] = ((const f16x8*)wcD0)[i];
  for (int i = tid; i < 2304; i += 512)
    ((f16x8*)(smem + 49152))[i] = ((const f16x8*)wgD1)[i];
  for (int i = tid; i < 1152; i += 512)
    ((f16x8*)(smem + 86016))[i] = ((const f16x8*)wcD1)[i];
  // d0 gate weights (streamed; r9 placement)
  f16x8 aR0[12], aU0[12];
#pragma unroll
  for (int ks = 0; ks < 12; ++ks) {
    aR0[ks] = ((const f16x8*)wgD0)[(cot4 * 12 + ks) * 64 + l];
    aU0[ks] = ((const f16x8*)wgD0)[((cot4 + 4) * 12 + ks) * 64 + l];
  }
  // dec biases
  f32x4 bRd0, bUd0, bCd0, bRd1, bUd1, bCd1;
#pragma unroll
  for (int q = 0; q < 4; ++q) {
    bRd0[q] = bgD0[co4 + q] * KSG;
    bUd0[q] = bgD0[64 + co4 + q] * KSG;
    bCd0[q] = bcD0[co4 + q] * KTH;
    bRd1[q] = bgD1[co2 + q] * KSG;
    bUd1[q] = bgD1[32 + co2 + q] * KSG;
    bCd1[q] = bcD1[co2 + q] * KTH;
  }
  const f16* cD0l = (const f16*)(smem + 0) + (cot4 * 12) * 512 + l * 8;
  const f16* gD1R = (const f16*)(smem + 49152) + (cot2 * 9) * 512 + l * 8;
  const f16* gD1U = (const f16*)(smem + 49152) + ((2 + cot2) * 9) * 512 + l * 8;
  const f16* cD1l = (const f16*)(smem + 86016) + (cot2 * 9) * 512 + l * 8;
  const float fb0 = fb[0];
  __syncthreads();
  {  // ingest y1(0)
    const f16x8* src = (const f16x8*)(y1g + (size_t)b * T_ * 8192);
#pragma unroll
    for (int k2 = 0; k2 < 2; ++k2) {
      const int i = tid + k2 * 512;
      *(f16x8*)&aT[(i >> 7) * CBSTR + ((i & 127) + 1) * 8] = src[i];
    }
  }
  __syncthreads();

  // ================= decoder (4 windows/t; out shifted 1 window) ===========
  for (int t = 0; t < T_; ++t) {
    // W2: d0 convA + postA ; out(t-1) (cb16-19 stable) ; issue y1(t+1)
    f32x4 aRd0[4], aUd0[4];
    convA_f<2, 4, 12, 4, true>(rdB4, aR0, aU0, nullptr, nullptr, aRd0, aUd0);
    if (t >= 1 && tid < F_) {
      float s = fb0;
#pragma unroll
      for (int cb = 0; cb < 4; ++cb) {
        const f16x8 h8 = *(const f16x8*)&aT[(16 + cb) * CBSTR + (tid + 1) * 8];
#pragma unroll
        for (int q = 0; q < 8; ++q) s = fmaf(fw[cb * 8 + q], (float)h8[q], s);
      }
      out[((size_t)b * T_ + (t - 1)) * F_ + tid] = s;
    }
    f16x8 yp0 = {}, yp1 = {};
    if (t + 1 < T_) {
      const f16x8* src = (const f16x8*)(y1g + ((size_t)b * T_ + t + 1) * 8192);
      yp0 = src[tid];
      yp1 = src[tid + 512];
    }
    postA_f<4, 20>(aRd0, bRd0, h1r, wrB4);
    __syncthreads();
    // W3: d0 convB + postB
    f32x4 aCd0[4];
    convB_f<2, 4, 12, 4, false>(rdB4, nullptr, cD0l, aCd0);
    postB_f<4, 8, false>(aUd0, aCd0, bUd0, bCd0, h1r, wrB4, nullptr);
    __syncthreads();
    // W4: d1 convA + postA ; write y1(t+1) -> cb0-7 (not read here)
    f32x4 aRd1[2], aUd1[2];
    convA_f<3, 2, 9, 3, false>(rdB2, nullptr, nullptr, gD1R, gD1U, aRd1, aUd1);
    if (t + 1 < T_) {
      const int i0 = tid, i1 = tid + 512;
      *(f16x8*)&aT[(i0 >> 7) * CBSTR + ((i0 & 127) + 1) * 8] = yp0;
      *(f16x8*)&aT[(i1 >> 7) * CBSTR + ((i1 & 127) + 1) * 8] = yp1;
    }
    postA_f<2, 20>(aRd1, bRd1, h0r, wrB2);
    __syncthreads();
    // W5: d1 convB + postB
    f32x4 aCd1[2];
    convB_f<3, 2, 9, 3, false>(rdB2, nullptr, cD1l, aCd1);
    postB_f<2, 16, false>(aUd1, aCd1, bUd1, bCd1, h0r, wrB2, nullptr);
    __syncthreads();
  }
  if (tid < F_) {  // epilogue: out(T-1)
    float s = fb0;
#pragma unroll
    for (int cb = 0; cb < 4; ++cb) {
      const f16x8 h8 = *(const f16x8*)&aT[(16 + cb) * CBSTR + (tid + 1) * 8];
#pragma unroll
      for (int q = 0; q < 8; ++q) s = fmaf(fw[cb * 8 + q], (float)h8[q], s);
    }
    out[((size_t)b * T_ + (T_ - 1)) * F_ + tid] = s;
  }
}

// ---------------- merged prologue ----------------
// (CO,CI,3,3) fp32 -> f16 packed per MFMA A-fragment:
// dst[((cot*NK+ks)*64+lane)*8+j] = W[cot*16+(lane&15)][kk=ks*32+(lane>>4)*8+j]
__device__ __forceinline__ void repack_one(const float* __restrict__ src,
                                           f16* __restrict__ dst, int i,
                                           int CI, int CINH, int NK, int e0map) {
  const int cot = i / (NK * 64);
  const int r = i - cot * NK * 64;
  const int ks = r >> 6, lph = r & 63;
  const int co = cot * 16 + (lph & 15);
  const int kbl = lph >> 4;
#pragma unroll
  for (int j = 0; j < 8; ++j) {
    const int kk = ks * 32 + kbl * 8 + j;
    const int k = kk / CINH, c = kk - k * CINH;
    int ci;
    if (e0map) ci = (c == 0) ? 0 : ((c >= 8 && c < 40) ? c - 7 : -1);
    else ci = (c < CI) ? c : -1;
    float wv = 0.f;
    if (ci >= 0) wv = src[((size_t)(co * CI + ci) * 3 + k) * 3 + 1];
    dst[(size_t)i * 8 + j] = (f16)wv;
  }
}

#define NX4 (B_ * T_ * F_ / 4)  // 204800 float4 items for x conversion

__global__ void prep_kernel(const float* __restrict__ x, f16* __restrict__ xf,
                            const float* s0, f16* d0, const float* s1, f16* d1,
                            const float* s2, f16* d2, const float* s3, f16* d3,
                            const float* s4, f16* d4, const float* s5, f16* d5,
                            const float* s6, f16* d6, const float* s7, f16* d7) {
  const int i = blockIdx.x * blockDim.x + threadIdx.x;
  if (i < NX4) {
    const float4 v = ((const float4*)x)[i];
    f16x4 o;
    o[0] = (f16)v.x; o[1] = (f16)v.y; o[2] = (f16)v.z; o[3] = (f16)v.w;
    ((f16x4*)xf)[i] = o;
    return;
  }
  int j = i - NX4;
  if (j < 1536) { repack_one(s0, d0, j, 33, 64, 6, 1); return; }   // e0 gates
  j -= 1536;
  if (j < 768) { repack_one(s1, d1, j, 33, 64, 6, 1); return; }    // e0 cand
  j -= 768;
  if (j < 4608) { repack_one(s2, d2, j, 96, 96, 9, 0); return; }   // e1 gates
  j -= 4608;
  if (j < 2304) { repack_one(s3, d3, j, 96, 96, 9, 0); return; }   // e1 cand
  j -= 2304;
  if (j < 6144) { repack_one(s4, d4, j, 128, 128, 12, 0); return; }  // d0 gates
  j -= 6144;
  if (j < 3072) { repack_one(s5, d5, j, 128, 128, 12, 0); return; }  // d0 cand
  j -= 3072;
  if (j < 2304) { repack_one(s6, d6, j, 96, 96, 9, 0); return; }   // d1 gates
  j -= 2304;
  if (j < 1152) { repack_one(s7, d7, j, 96, 96, 9, 0); return; }   // d1 cand
}

extern "C" void kernel_launch(void* const* d_in, const int* in_sizes, int n_in,
                              void* d_out, int out_size, void* d_ws, size_t ws_size,
                              hipStream_t stream) {
  (void)in_sizes; (void)n_in; (void)out_size; (void)ws_size;
  const float* x = (const float*)d_in[0];
  const float* e0_wg = (const float*)d_in[1];
  const float* e0_bg = (const float*)d_in[2];
  const float* e0_wc = (const float*)d_in[3];
  const float* e0_bc = (const float*)d_in[4];
  const float* e1_wg = (const float*)d_in[5];
  const float* e1_bg = (const float*)d_in[6];
  const float* e1_wc = (const float*)d_in[7];
  const float* e1_bc = (const float*)d_in[8];
  const float* d0_wg = (const float*)d_in[9];
  const float* d0_bg = (const float*)d_in[10];
  const float* d0_wc = (const float*)d_in[11];
  const float* d0_bc = (const float*)d_in[12];
  const float* d1_wg = (const float*)d_in[13];
  const float* d1_bg = (const float*)d_in[14];
  const float* d1_wc = (const float*)d_in[15];
  const float* d1_bc = (const float*)d_in[16];
  const float* fw = (const float*)d_in[17];
  const float* fb = (const float*)d_in[18];
  float* out = (float*)d_out;

  char* p = (char*)d_ws;
  f16* y1g = (f16*)p;
  p += (size_t)B_ * T_ * 64 * 128 * 2;  // 104.86 MB
  f16* xf = (f16*)p;
  p += (size_t)B_ * T_ * F_ * 2;        // 1.64 MB
  auto aw = [&](int n) { f16* q = (f16*)p; p += (size_t)n * 2; return q; };
  f16* wgE0 = aw(64 * 192);
  f16* wcE0 = aw(32 * 192);
  f16* wgE1 = aw(128 * 288);
  f16* wcE1 = aw(64 * 288);
  f16* wgD0 = aw(128 * 384);
  f16* wcD0 = aw(64 * 384);
  f16* wgD1 = aw(64 * 288);
  f16* wcD1 = aw(32 * 288);

  const int prep_items = NX4 + 21888;
  hipLaunchKernelGGL(prep_kernel, dim3((prep_items + 1023) / 1024), dim3(1024),
                     0, stream, x, xf,
                     e0_wg, wgE0, e0_wc, wcE0,
                     e1_wg, wgE1, e1_wc, wcE1,
                     d0_wg, wgD0, d0_wc, wcD0,
                     d1_wg, wgD1, d1_wc, wcD1);

  hipFuncSetAttribute((const void*)ae_kernel,
                      hipFuncAttributeMaxDynamicSharedMemorySize, LDS_TOTAL);
  hipLaunchKernelGGL(ae_kernel, dim3(B_), dim3(512), LDS_TOTAL, stream, xf, out,
                     wgE0, wcE0, e0_bg, e0_bc, wgE1, wcE1, e1_bg, e1_bc,
                     wgD0, wcD0, d0_bg, d0_bc, wgD1, wcD1, d1_bg, d1_bc,
                     fw, fb, y1g);
}